// Round 16
// baseline (514.053 us; speedup 1.0000x reference)
//
#include <hip/hip_runtime.h>
#include <math.h>

#define NRES 768
#define C    128
#define LNEPS 1e-5f
#define TA   16             // a-values per block (phase A)
#define ACH  48             // a-chunks = 768/TA
#define MI   32             // i-rows per block (phase A)
#define NIT  (NRES / MI)    // 24 i-tiles
#define XBUF (MI * 256)     // bytes per LDS plane (phase A)
#define LHALF (ACH * NIT)   // blocks per half in line_all
#define OSC  0.015625f      // 1/64: out-kernel staging scale (fp16 range guard)

typedef __attribute__((ext_vector_type(8))) _Float16 f16x8;
typedef __attribute__((ext_vector_type(4))) float   f32x4;

// pack two f32 -> two f16 (RTN) in one dword
__device__ __forceinline__ uint32_t pk_f16rn(float a, float b) {
    _Float16 ha = (_Float16)a, hb = (_Float16)b;   // RTN converts
    const uint32_t ua = *(const unsigned short*)&ha;
    const uint32_t ub = *(const unsigned short*)&hb;
    return ua | (ub << 16);
}

// Stage one row-segment (4 cols) of row `row` as f16 value + f16 square
// planes, XOR-swizzled. Pure local VALU + ds_write; no cross-lane ops.
__device__ __forceinline__ void stage_row2(const float4& x, int row, int t,
                                           char* hiB, char* sqB) {
    const int byte = (row * 256 + 8 * (t & 31)) ^ ((row & 15) << 4);
    uint2 uh, uq;
    uh.x = pk_f16rn(x.x, x.y);
    uh.y = pk_f16rn(x.z, x.w);
    uq.x = pk_f16rn(x.x * x.x, x.y * x.y);
    uq.y = pk_f16rn(x.z * x.z, x.w * x.w);
    *(uint2*)(hiB + byte) = uh;
    *(uint2*)(sqB + byte) = uq;
}

// ---------------------------------------------------------------------------
// Phase A (both halves in ONE launch): partial line sums.
// line[i,c] = sum_a [mask[a,i]] * P(a,i,c) * sigmoid(G(a,i,c))
// [P|G](a,i,:) = LN(act[a,i,:]) @ [wP|wG] + bias
// LN folded: P_n = inv*(x@W'q - m*sumW'q) + (b@W + bias), W'q = f16(g_k W_kn).
// Row stats BY MFMA: Sx = mfma(x_f16, ones), Sx^2 = mfma(f16(x^2), ones).
// MI=32 (vs R13's 16): per-step compute window doubles (48 MFMA + 2x
// epilogue) so the single-step register prefetch covers HBM latency —
// R13's 16-row step was too short and exposed vmcnt stalls. Register
// shape mirrors R4's proven-fitting MI=32 layout (acc scoped per mt).
// Blocks 0..LHALF-1: act_s -> part[0]; LHALF..: act_r (masked) -> part[1].
// ---------------------------------------------------------------------------
__global__ __launch_bounds__(256, 3) void line_all(
    const float* __restrict__ act_s, const float* __restrict__ act_r,
    const float* __restrict__ mask,
    const float* __restrict__ ln_g, const float* __restrict__ ln_b,
    const float* __restrict__ w_lp, const float* __restrict__ b_lp,
    const float* __restrict__ w_rp, const float* __restrict__ b_rp,
    const float* __restrict__ w_lg, const float* __restrict__ b_lg,
    const float* __restrict__ w_rg, const float* __restrict__ b_rg,
    float* __restrict__ part)        // [2][ACH][768][128]
{
    __shared__ char  sHi[XBUF];      // f16 [32 rows][128 c], XOR-swizzled
    __shared__ char  sSq[XBUF];
    __shared__ float sM[TA * MI];

    const int t = threadIdx.x;
    const int w = t >> 6;            // wave 0..3
    const int l = t & 63;
    const int right = (blockIdx.x >= LHALF);
    const int bid2  = blockIdx.x - right * LHALF;
    const int i0  = (bid2 % NIT) * MI;
    const int ach = bid2 / NIT;
    const int a0  = ach * TA;

    const float* act = right ? act_r : act_s;
    const float* wP  = right ? w_rp : w_lp;
    const float* bP  = right ? b_rp : b_lp;
    const float* wG  = right ? w_rg : w_lg;
    const float* bG  = right ? b_rg : b_lg;

    // --- B-fragments: W'q = f16(g_k*W[k][n]); per-col constants:
    //     sQ[nt] = sum_k W'q[k][n], cB[nt] = sum_k b_k*W[k][n] + bias_n
    f16x8 bfr[4][4];                 // [nt][kk]; nt 0,1 = P, nt 2,3 = G
    float sQ[4], cB[4];
#pragma unroll
    for (int nt = 0; nt < 4; ++nt) {
        const float* wsrc = (nt < 2) ? wP : wG;
        const int n = w * 32 + (nt & 1) * 16 + (l & 15);
        float sacc = 0.f, tacc = 0.f;
#pragma unroll
        for (int kk = 0; kk < 4; ++kk) {
            f16x8 f;
#pragma unroll
            for (int jj = 0; jj < 8; ++jj) {
                const int k = kk * 32 + (l >> 4) * 8 + jj;
                const float wv = wsrc[k * C + n];
                const _Float16 q = (_Float16)(ln_g[k] * wv);   // RTN
                f[jj] = q;
                sacc += (float)q;
                tacc += ln_b[k] * wv;
            }
            bfr[nt][kk] = f;
        }
        // complete the k-sum over the 4 lane-groups sharing this n
        sacc += __shfl_xor(sacc, 16); sacc += __shfl_xor(sacc, 32);
        tacc += __shfl_xor(tacc, 16); tacc += __shfl_xor(tacc, 32);
        sQ[nt] = sacc;
        cB[nt] = tacc + ((nt < 2) ? bP[n] : bG[n]);
    }

    f16x8 onesf;
#pragma unroll
    for (int jj = 0; jj < 8; ++jj) onesf[jj] = (_Float16)1.0f;

    if (right) {
        // sM[al*32 + r] = mask[a0+al][i0+r]
        for (int idx = t; idx < TA * MI; idx += 256)
            sM[idx] = mask[(size_t)(a0 + (idx >> 5)) * NRES + i0 + (idx & 31)];
    }

    float lacc[2][2][4];
#pragma unroll
    for (int mt = 0; mt < 2; ++mt)
#pragma unroll
        for (int ntp = 0; ntp < 2; ++ntp)
#pragma unroll
            for (int jr = 0; jr < 4; ++jr) lacc[mt][ntp][jr] = 0.f;

    const float* srcbase = act + (size_t)a0 * (NRES * C) + (size_t)i0 * C;

    // prologue: load a=0 (4 float4/thread covers 32 rows x 128 c)
    float4 xv[4], xn[4];
#pragma unroll
    for (int j = 0; j < 4; ++j)
        xv[j] = *(const float4*)(srcbase + 4 * (t + 256 * j));

    for (int al = 0; al < TA; ++al) {
        // issue next step's loads early (consumed only at next stage)
        if (al + 1 < TA) {
            const float* srcn = srcbase + (size_t)(al + 1) * (NRES * C);
#pragma unroll
            for (int j = 0; j < 4; ++j)
                xn[j] = *(const float4*)(srcn + 4 * (t + 256 * j));
        }

#pragma unroll
        for (int j = 0; j < 4; ++j)
            stage_row2(xv[j], (t >> 5) + 8 * j, t, sHi, sSq);
        __syncthreads();

        const f32x4 zero = {0.f, 0.f, 0.f, 0.f};
#pragma unroll
        for (int mt = 0; mt < 2; ++mt) {
            f32x4 acc[4], accS = zero, accS2 = zero;
#pragma unroll
            for (int nt = 0; nt < 4; ++nt) acc[nt] = zero;

#pragma unroll
            for (int kk = 0; kk < 4; ++kk) {
                const int row  = mt * 16 + (l & 15);
                const int byte = (row * 256 + (kk * 32 + (l >> 4) * 8) * 2) ^ ((row & 15) << 4);
                const f16x8 ah  = *(const f16x8*)(sHi + byte);
                const f16x8 asq = *(const f16x8*)(sSq + byte);
                acc[0] = __builtin_amdgcn_mfma_f32_16x16x32_f16(ah,  bfr[0][kk], acc[0], 0, 0, 0);
                acc[1] = __builtin_amdgcn_mfma_f32_16x16x32_f16(ah,  bfr[1][kk], acc[1], 0, 0, 0);
                acc[2] = __builtin_amdgcn_mfma_f32_16x16x32_f16(ah,  bfr[2][kk], acc[2], 0, 0, 0);
                acc[3] = __builtin_amdgcn_mfma_f32_16x16x32_f16(ah,  bfr[3][kk], acc[3], 0, 0, 0);
                accS   = __builtin_amdgcn_mfma_f32_16x16x32_f16(ah,  onesf, accS,  0, 0, 0);
                accS2  = __builtin_amdgcn_mfma_f32_16x16x32_f16(asq, onesf, accS2, 0, 0, 0);
            }

            float mk[4] = {1.f, 1.f, 1.f, 1.f};
            if (right) {
                const float4 m4 = *(const float4*)&sM[al * MI + mt * 16 + (l >> 4) * 4];
                mk[0] = m4.x; mk[1] = m4.y; mk[2] = m4.z; mk[3] = m4.w;
            }
#pragma unroll
            for (int jr = 0; jr < 4; ++jr) {
                const float m_  = accS[jr] * (1.f / C);
                const float var = accS2[jr] * (1.f / C) - m_ * m_;
                const float inv = rsqrtf(var + LNEPS);
#pragma unroll
                for (int ntp = 0; ntp < 2; ++ntp) {
                    const float P = (acc[ntp][jr]     - m_ * sQ[ntp])     * inv + cB[ntp];
                    const float G = (acc[ntp + 2][jr] - m_ * sQ[ntp + 2]) * inv + cB[ntp + 2];
                    const float sg = __builtin_amdgcn_rcpf(1.f + __expf(-G));
                    lacc[mt][ntp][jr] += P * sg * mk[jr];
                }
            }
        }
        __syncthreads();   // all waves done reading planes before next stage

#pragma unroll
        for (int j = 0; j < 4; ++j) xv[j] = xn[j];
    }

    float* dst = part + ((size_t)right * ACH + ach) * (NRES * C);
#pragma unroll
    for (int mt = 0; mt < 2; ++mt)
#pragma unroll
        for (int ntp = 0; ntp < 2; ++ntp)
#pragma unroll
            for (int jr = 0; jr < 4; ++jr)
                dst[(size_t)(i0 + mt * 16 + (l >> 4) * 4 + jr) * C +
                    w * 32 + ntp * 16 + (l & 15)] = lacc[mt][ntp][jr];
}

// both halves reduced in one launch: blocks 0..383 -> left, 384..767 -> right
__global__ __launch_bounds__(256) void reduce2(const float* __restrict__ part,
                                               float* __restrict__ left_line,
                                               float* __restrict__ right_line) {
    const int half = (blockIdx.x >= 384);
    const int idx  = (blockIdx.x - half * 384) * 256 + threadIdx.x;  // < 98304
    const float* p = part + (size_t)half * ACH * NRES * C;
    float s = 0.f;
#pragma unroll 8
    for (int q = 0; q < ACH; ++q) s += p[(size_t)q * (NRES * C) + idx];
    (half ? right_line : left_line)[idx] = s;
}

// ---------------------------------------------------------------------------
// Phase B: out[i,j,:] = LN(l[i,:]*r[j,:]) @ w_out + b_out
// LN-fold as phase A, fp16 operands. RANGE GUARD: stage p' = p/64 (LN is
// scale-invariant with eps' = eps/64^2) — unscaled p*p overflowed fp16.
// One block per i (768 blocks), looping 12 j-tiles so the W-frag preamble
// amortizes 12x.
// ---------------------------------------------------------------------------
__global__ __launch_bounds__(256, 3) void out_mfma(
    const float* __restrict__ lline,   // [768,128]
    const float* __restrict__ rline,   // [768,128]
    const float* __restrict__ cg, const float* __restrict__ cb,
    const float* __restrict__ wO, const float* __restrict__ bO,
    float* __restrict__ out)           // [768,768,128]
{
    __shared__ char sHi[64 * 256];
    __shared__ char sSq[64 * 256];

    const int t = threadIdx.x;
    const int w = t >> 6;
    const int l = t & 63;
    const int i = blockIdx.x;

    f16x8 bfr[2][4];
    float sQ[2], cB[2];
#pragma unroll
    for (int nt = 0; nt < 2; ++nt) {
        const int n = w * 32 + nt * 16 + (l & 15);
        float sacc = 0.f, tacc = 0.f;
#pragma unroll
        for (int kk = 0; kk < 4; ++kk) {
            f16x8 f;
#pragma unroll
            for (int jj = 0; jj < 8; ++jj) {
                const int k = kk * 32 + (l >> 4) * 8 + jj;
                const float wv = wO[k * C + n];
                const _Float16 q = (_Float16)(cg[k] * wv);   // RTN
                f[jj] = q;
                sacc += (float)q;
                tacc += cb[k] * wv;
            }
            bfr[nt][kk] = f;
        }
        sacc += __shfl_xor(sacc, 16); sacc += __shfl_xor(sacc, 32);
        tacc += __shfl_xor(tacc, 16); tacc += __shfl_xor(tacc, 32);
        sQ[nt] = sacc;
        cB[nt] = tacc + bO[n];
    }

    f16x8 onesf;
#pragma unroll
    for (int jj = 0; jj < 8; ++jj) onesf[jj] = (_Float16)1.0f;

    const int c4 = 4 * (t & 31);
    // fold the 1/64 staging scale into the left-line preload
    float4 l4 = *(const float4*)(lline + (size_t)i * C + c4);
    l4.x *= OSC; l4.y *= OSC; l4.z *= OSC; l4.w *= OSC;

    for (int jt = 0; jt < 12; ++jt) {
        const int j0 = jt * 64;
        const float* rsrc = rline + (size_t)j0 * C;

        // hoist the 8 tile loads, then convert+stage
        float4 rv[8];
#pragma unroll
        for (int j = 0; j < 8; ++j)
            rv[j] = *(const float4*)(rsrc + 4 * (t + 256 * j));
#pragma unroll
        for (int j = 0; j < 8; ++j) {
            float4 p;
            p.x = l4.x * rv[j].x; p.y = l4.y * rv[j].y;
            p.z = l4.z * rv[j].z; p.w = l4.w * rv[j].w;
            stage_row2(p, (t >> 5) + 8 * j, t, sHi, sSq);
        }
        __syncthreads();

        const f32x4 zero = {0.f, 0.f, 0.f, 0.f};
#pragma unroll
        for (int mt = 0; mt < 4; ++mt) {
            f32x4 acc[2], accS = zero, accS2 = zero;
#pragma unroll
            for (int nt = 0; nt < 2; ++nt) acc[nt] = zero;
#pragma unroll
            for (int kk = 0; kk < 4; ++kk) {
                const int row  = mt * 16 + (l & 15);
                const int byte = (row * 256 + (kk * 32 + (l >> 4) * 8) * 2) ^ ((row & 15) << 4);
                const f16x8 ah  = *(const f16x8*)(sHi + byte);
                const f16x8 asq = *(const f16x8*)(sSq + byte);
                acc[0] = __builtin_amdgcn_mfma_f32_16x16x32_f16(ah,  bfr[0][kk], acc[0], 0, 0, 0);
                acc[1] = __builtin_amdgcn_mfma_f32_16x16x32_f16(ah,  bfr[1][kk], acc[1], 0, 0, 0);
                accS   = __builtin_amdgcn_mfma_f32_16x16x32_f16(ah,  onesf, accS,  0, 0, 0);
                accS2  = __builtin_amdgcn_mfma_f32_16x16x32_f16(asq, onesf, accS2, 0, 0, 0);
            }
#pragma unroll
            for (int jr = 0; jr < 4; ++jr) {
                const float m_  = accS[jr] * (1.f / C);
                const float var = accS2[jr] * (1.f / C) - m_ * m_;
                const float inv = rsqrtf(var + LNEPS * OSC * OSC);  // eps' = eps/64^2
#pragma unroll
                for (int nt = 0; nt < 2; ++nt)
                    out[((size_t)i * NRES + j0 + mt * 16 + (l >> 4) * 4 + jr) * C +
                        w * 32 + nt * 16 + (l & 15)] =
                        (acc[nt][jr] - m_ * sQ[nt]) * inv + cB[nt];
            }
        }
        __syncthreads();   // protect planes before next tile's stage
    }
}

extern "C" void kernel_launch(void* const* d_in, const int* in_sizes, int n_in,
                              void* d_out, int out_size, void* d_ws, size_t ws_size,
                              hipStream_t stream) {
    const float* act_s = (const float*)d_in[0];
    const float* act_r = (const float*)d_in[1];
    const float* mask  = (const float*)d_in[2];
    const float* ln_g  = (const float*)d_in[3];
    const float* ln_b  = (const float*)d_in[4];
    const float* w_lp  = (const float*)d_in[5];
    const float* b_lp  = (const float*)d_in[6];
    const float* w_rp  = (const float*)d_in[7];
    const float* b_rp  = (const float*)d_in[8];
    const float* w_lg  = (const float*)d_in[9];
    const float* b_lg  = (const float*)d_in[10];
    const float* w_rg  = (const float*)d_in[11];
    const float* b_rg  = (const float*)d_in[12];
    const float* ln_cg = (const float*)d_in[13];
    const float* ln_cb = (const float*)d_in[14];
    const float* w_out = (const float*)d_in[15];
    const float* b_out = (const float*)d_in[16];
    float* out = (float*)d_out;

    float* part       = (float*)d_ws;              // [2][ACH][768][128]
    float* left_line  = part + (size_t)2 * ACH * NRES * C;
    float* right_line = left_line + NRES * C;

    line_all<<<2 * LHALF, 256, 0, stream>>>(act_s, act_r, mask, ln_g, ln_b,
                                            w_lp, b_lp, w_rp, b_rp,
                                            w_lg, b_lg, w_rg, b_rg, part);
    reduce2<<<768, 256, 0, stream>>>(part, left_line, right_line);
    out_mfma<<<NRES, 256, 0, stream>>>(left_line, right_line, ln_cg, ln_cb,
                                       w_out, b_out, out);
}

// Round 17
// 391.160 us; speedup vs baseline: 1.3142x; 1.3142x over previous
//
#include <hip/hip_runtime.h>
#include <math.h>

#define NRES 768
#define C    128
#define LNEPS 1e-5f
#define TA   16             // a-values per block (phase A)
#define ACH  48             // a-chunks = 768/TA
#define MI   16             // i-rows per block (phase A)
#define NIT  (NRES / MI)    // 48 i-tiles
#define LHALF (ACH * NIT)   // blocks per half in line_all
#define ASTRIDE (NRES * C * 4)   // bytes between consecutive a-planes
#define OSC  0.015625f      // 1/64: out-kernel staging scale (fp16 range guard)

#define AS1 __attribute__((address_space(1)))
#define AS3 __attribute__((address_space(3)))

typedef __attribute__((ext_vector_type(8))) _Float16 f16x8;
typedef __attribute__((ext_vector_type(4))) float   f32x4;

// pack two f32 -> two f16 (RTN) in one dword (out_mfma staging)
__device__ __forceinline__ uint32_t pk_f16rn(float a, float b) {
    _Float16 ha = (_Float16)a, hb = (_Float16)b;
    const uint32_t ua = *(const unsigned short*)&ha;
    const uint32_t ub = *(const unsigned short*)&hb;
    return ua | (ub << 16);
}

// out_mfma: stage one 4-col row-segment as f16 value + f16 square planes
__device__ __forceinline__ void stage_row2(const float4& x, int row, int t,
                                           char* hiB, char* sqB) {
    const int byte = (row * 256 + 8 * (t & 31)) ^ ((row & 15) << 4);
    uint2 uh, uq;
    uh.x = pk_f16rn(x.x, x.y);
    uh.y = pk_f16rn(x.z, x.w);
    uq.x = pk_f16rn(x.x * x.x, x.y * x.y);
    uq.y = pk_f16rn(x.z * x.z, x.w * x.w);
    *(uint2*)(hiB + byte) = uh;
    *(uint2*)(sqB + byte) = uq;
}

// ---------------------------------------------------------------------------
// Phase A (both halves in ONE launch): partial line sums.
// line[i,c] = sum_a [mask[a,i]] * P(a,i,c) * sigmoid(G(a,i,c))
// [P|G](a,i,:) = LN(act[a,i,:]) @ [wP|wG] + bias ; LN folded into the matmul.
// Staging: RAW f32 tile (16x128 = 8KB) DMA'd global->LDS via
// global_load_lds width=16 (no VGPR round-trip, no register rotation).
// Swizzle both-sides (rule #21): LDS dest linear, global SOURCE address
// pre-XOR'd with ((row&7)<<4); frag reads apply the same XOR (involution).
// f32->f16 (x and x^2) conversion happens in registers at consume time.
// Double-buffered, ONE barrier per a-step (m97 K-loop structure):
//   issue DMA(al+1 -> nxt) ; consume cur (ds_read+cvt+MFMA+epilogue) ; barrier
// Blocks 0..LHALF-1: act_s -> part[0]; LHALF..: act_r (masked) -> part[1].
// ---------------------------------------------------------------------------
__global__ __launch_bounds__(256, 3) void line_all(
    const float* __restrict__ act_s, const float* __restrict__ act_r,
    const float* __restrict__ mask,
    const float* __restrict__ ln_g, const float* __restrict__ ln_b,
    const float* __restrict__ w_lp, const float* __restrict__ b_lp,
    const float* __restrict__ w_rp, const float* __restrict__ b_rp,
    const float* __restrict__ w_lg, const float* __restrict__ b_lg,
    const float* __restrict__ w_rg, const float* __restrict__ b_rg,
    float* __restrict__ part)        // [2][ACH][768][128]
{
    __shared__ __align__(16) char sA[8192];   // raw f32 [16][128], src-swizzled
    __shared__ __align__(16) char sB[8192];
    __shared__ float sM[TA * MI];

    const int t = threadIdx.x;
    const int w = t >> 6;            // wave 0..3
    const int l = t & 63;
    const int right = (blockIdx.x >= LHALF);
    const int bid2  = blockIdx.x - right * LHALF;
    const int i0  = (bid2 % NIT) * MI;
    const int ach = bid2 / NIT;
    const int a0  = ach * TA;

    const float* act = right ? act_r : act_s;
    const float* wP  = right ? w_rp : w_lp;
    const float* bP  = right ? b_rp : b_lp;
    const float* wG  = right ? w_rg : w_lg;
    const float* bG  = right ? b_rg : b_lg;

    // --- B-fragments: W'q = f16(g_k*W[k][n]); per-col constants ---
    f16x8 bfr[4][4];                 // [nt][kk]; nt 0,1 = P, nt 2,3 = G
    float sQ[4], cB[4];
#pragma unroll
    for (int nt = 0; nt < 4; ++nt) {
        const float* wsrc = (nt < 2) ? wP : wG;
        const int n = w * 32 + (nt & 1) * 16 + (l & 15);
        float sacc = 0.f, tacc = 0.f;
#pragma unroll
        for (int kk = 0; kk < 4; ++kk) {
            f16x8 f;
#pragma unroll
            for (int jj = 0; jj < 8; ++jj) {
                const int k = kk * 32 + (l >> 4) * 8 + jj;
                const float wv = wsrc[k * C + n];
                const _Float16 q = (_Float16)(ln_g[k] * wv);   // RTN
                f[jj] = q;
                sacc += (float)q;
                tacc += ln_b[k] * wv;
            }
            bfr[nt][kk] = f;
        }
        sacc += __shfl_xor(sacc, 16); sacc += __shfl_xor(sacc, 32);
        tacc += __shfl_xor(tacc, 16); tacc += __shfl_xor(tacc, 32);
        sQ[nt] = sacc;
        cB[nt] = tacc + ((nt < 2) ? bP[n] : bG[n]);
    }

    f16x8 onesf;
#pragma unroll
    for (int jj = 0; jj < 8; ++jj) onesf[jj] = (_Float16)1.0f;

    if (right) {
        sM[t] = mask[(size_t)(a0 + (t >> 4)) * NRES + i0 + (t & 15)];
    }

    float lacc[2][4];
#pragma unroll
    for (int ntp = 0; ntp < 2; ++ntp)
#pragma unroll
        for (int jr = 0; jr < 4; ++jr) lacc[ntp][jr] = 0.f;

    const char* srcbase = (const char*)(act + (size_t)a0 * (NRES * C) + (size_t)i0 * C);

    // per-lane DMA source addresses (pre-swizzled so linear LDS dest yields
    // the swizzled layout); each wave stages bytes [w*2048, w*2048+2048)
    const int lin0 = w * 2048 + l * 16;
    const int lin1 = lin0 + 1024;
    const int sw0  = lin0 ^ (((lin0 >> 9) & 7) << 4);
    const int sw1  = lin1 ^ (((lin1 >> 9) & 7) << 4);
    const char* gq0 = srcbase + sw0;
    const char* gq1 = srcbase + sw1;

    // prologue: DMA a=0 into sA
    __builtin_amdgcn_global_load_lds((const AS1 uint32_t*)gq0,
                                     (AS3 uint32_t*)(sA + w * 2048), 16, 0, 0);
    __builtin_amdgcn_global_load_lds((const AS1 uint32_t*)gq1,
                                     (AS3 uint32_t*)(sA + w * 2048 + 1024), 16, 0, 0);
    gq0 += ASTRIDE; gq1 += ASTRIDE;
    __syncthreads();

    const int r  = l & 15;
    const int rx = l & 7;            // swizzle key (row&7)

    for (int al = 0; al < TA; ++al) {
        const char* cur = (al & 1) ? sB : sA;
        char*       nxt = (al & 1) ? sA : sB;

        // issue next a-step's DMA first (covered by this step's compute)
        if (al + 1 < TA) {
            __builtin_amdgcn_global_load_lds((const AS1 uint32_t*)gq0,
                                             (AS3 uint32_t*)(nxt + w * 2048), 16, 0, 0);
            __builtin_amdgcn_global_load_lds((const AS1 uint32_t*)gq1,
                                             (AS3 uint32_t*)(nxt + w * 2048 + 1024), 16, 0, 0);
            gq0 += ASTRIDE; gq1 += ASTRIDE;
        }

        const f32x4 zero = {0.f, 0.f, 0.f, 0.f};
        f32x4 acc[4], accS = zero, accS2 = zero;
#pragma unroll
        for (int nt = 0; nt < 4; ++nt) acc[nt] = zero;

#pragma unroll
        for (int kk = 0; kk < 4; ++kk) {
            const int ch0 = kk * 8 + (l >> 4) * 2;
            const int ad0 = r * 512 + (((ch0)     ^ rx) << 4);
            const int ad1 = r * 512 + (((ch0 + 1) ^ rx) << 4);
            const float4 xa = *(const float4*)(cur + ad0);   // cols +0..3
            const float4 xb = *(const float4*)(cur + ad1);   // cols +4..7

            f16x8 xf, qf;
            xf[0] = (_Float16)xa.x; xf[1] = (_Float16)xa.y;
            xf[2] = (_Float16)xa.z; xf[3] = (_Float16)xa.w;
            xf[4] = (_Float16)xb.x; xf[5] = (_Float16)xb.y;
            xf[6] = (_Float16)xb.z; xf[7] = (_Float16)xb.w;
            qf[0] = (_Float16)(xa.x * xa.x); qf[1] = (_Float16)(xa.y * xa.y);
            qf[2] = (_Float16)(xa.z * xa.z); qf[3] = (_Float16)(xa.w * xa.w);
            qf[4] = (_Float16)(xb.x * xb.x); qf[5] = (_Float16)(xb.y * xb.y);
            qf[6] = (_Float16)(xb.z * xb.z); qf[7] = (_Float16)(xb.w * xb.w);

            acc[0] = __builtin_amdgcn_mfma_f32_16x16x32_f16(xf, bfr[0][kk], acc[0], 0, 0, 0);
            acc[1] = __builtin_amdgcn_mfma_f32_16x16x32_f16(xf, bfr[1][kk], acc[1], 0, 0, 0);
            acc[2] = __builtin_amdgcn_mfma_f32_16x16x32_f16(xf, bfr[2][kk], acc[2], 0, 0, 0);
            acc[3] = __builtin_amdgcn_mfma_f32_16x16x32_f16(xf, bfr[3][kk], acc[3], 0, 0, 0);
            accS   = __builtin_amdgcn_mfma_f32_16x16x32_f16(xf, onesf, accS,  0, 0, 0);
            accS2  = __builtin_amdgcn_mfma_f32_16x16x32_f16(qf, onesf, accS2, 0, 0, 0);
        }

        float mk[4] = {1.f, 1.f, 1.f, 1.f};
        if (right) {
            const float4 m4 = *(const float4*)&sM[al * MI + (l >> 4) * 4];
            mk[0] = m4.x; mk[1] = m4.y; mk[2] = m4.z; mk[3] = m4.w;
        }
#pragma unroll
        for (int jr = 0; jr < 4; ++jr) {
            const float m_  = accS[jr] * (1.f / C);
            const float var = accS2[jr] * (1.f / C) - m_ * m_;
            const float inv = rsqrtf(var + LNEPS);
#pragma unroll
            for (int ntp = 0; ntp < 2; ++ntp) {
                const float P = (acc[ntp][jr]     - m_ * sQ[ntp])     * inv + cB[ntp];
                const float G = (acc[ntp + 2][jr] - m_ * sQ[ntp + 2]) * inv + cB[ntp + 2];
                const float sg = __builtin_amdgcn_rcpf(1.f + __expf(-G));
                lacc[ntp][jr] += P * sg * mk[jr];
            }
        }

        __syncthreads();   // drains DMA (nxt ready) + readers done with cur
    }

    float* dst = part + ((size_t)right * ACH + ach) * (NRES * C);
#pragma unroll
    for (int ntp = 0; ntp < 2; ++ntp)
#pragma unroll
        for (int jr = 0; jr < 4; ++jr)
            dst[(size_t)(i0 + (l >> 4) * 4 + jr) * C +
                w * 32 + ntp * 16 + (l & 15)] = lacc[ntp][jr];
}

// both halves reduced in one launch: blocks 0..383 -> left, 384..767 -> right
__global__ __launch_bounds__(256) void reduce2(const float* __restrict__ part,
                                               float* __restrict__ left_line,
                                               float* __restrict__ right_line) {
    const int half = (blockIdx.x >= 384);
    const int idx  = (blockIdx.x - half * 384) * 256 + threadIdx.x;  // < 98304
    const float* p = part + (size_t)half * ACH * NRES * C;
    float s = 0.f;
#pragma unroll 8
    for (int q = 0; q < ACH; ++q) s += p[(size_t)q * (NRES * C) + idx];
    (half ? right_line : left_line)[idx] = s;
}

// ---------------------------------------------------------------------------
// Phase B: out[i,j,:] = LN(l[i,:]*r[j,:]) @ w_out + b_out
// LN-fold, fp16 operands, p' = p/64 range guard (eps' = eps/64^2).
// One block per i (768 blocks), looping 12 j-tiles.
// ---------------------------------------------------------------------------
__global__ __launch_bounds__(256, 3) void out_mfma(
    const float* __restrict__ lline,   // [768,128]
    const float* __restrict__ rline,   // [768,128]
    const float* __restrict__ cg, const float* __restrict__ cb,
    const float* __restrict__ wO, const float* __restrict__ bO,
    float* __restrict__ out)           // [768,768,128]
{
    __shared__ char sHi[64 * 256];
    __shared__ char sSq[64 * 256];

    const int t = threadIdx.x;
    const int w = t >> 6;
    const int l = t & 63;
    const int i = blockIdx.x;

    f16x8 bfr[2][4];
    float sQ[2], cB[2];
#pragma unroll
    for (int nt = 0; nt < 2; ++nt) {
        const int n = w * 32 + nt * 16 + (l & 15);
        float sacc = 0.f, tacc = 0.f;
#pragma unroll
        for (int kk = 0; kk < 4; ++kk) {
            f16x8 f;
#pragma unroll
            for (int jj = 0; jj < 8; ++jj) {
                const int k = kk * 32 + (l >> 4) * 8 + jj;
                const float wv = wO[k * C + n];
                const _Float16 q = (_Float16)(cg[k] * wv);   // RTN
                f[jj] = q;
                sacc += (float)q;
                tacc += cb[k] * wv;
            }
            bfr[nt][kk] = f;
        }
        sacc += __shfl_xor(sacc, 16); sacc += __shfl_xor(sacc, 32);
        tacc += __shfl_xor(tacc, 16); tacc += __shfl_xor(tacc, 32);
        sQ[nt] = sacc;
        cB[nt] = tacc + bO[n];
    }

    f16x8 onesf;
#pragma unroll
    for (int jj = 0; jj < 8; ++jj) onesf[jj] = (_Float16)1.0f;

    const int c4 = 4 * (t & 31);
    float4 l4 = *(const float4*)(lline + (size_t)i * C + c4);
    l4.x *= OSC; l4.y *= OSC; l4.z *= OSC; l4.w *= OSC;

    for (int jt = 0; jt < 12; ++jt) {
        const int j0 = jt * 64;
        const float* rsrc = rline + (size_t)j0 * C;

        float4 rv[8];
#pragma unroll
        for (int j = 0; j < 8; ++j)
            rv[j] = *(const float4*)(rsrc + 4 * (t + 256 * j));
#pragma unroll
        for (int j = 0; j < 8; ++j) {
            float4 p;
            p.x = l4.x * rv[j].x; p.y = l4.y * rv[j].y;
            p.z = l4.z * rv[j].z; p.w = l4.w * rv[j].w;
            stage_row2(p, (t >> 5) + 8 * j, t, sHi, sSq);
        }
        __syncthreads();

        const f32x4 zero = {0.f, 0.f, 0.f, 0.f};
#pragma unroll
        for (int mt = 0; mt < 4; ++mt) {
            f32x4 acc[2], accS = zero, accS2 = zero;
#pragma unroll
            for (int nt = 0; nt < 2; ++nt) acc[nt] = zero;
#pragma unroll
            for (int kk = 0; kk < 4; ++kk) {
                const int row  = mt * 16 + (l & 15);
                const int byte = (row * 256 + (kk * 32 + (l >> 4) * 8) * 2) ^ ((row & 15) << 4);
                const f16x8 ah  = *(const f16x8*)(sHi + byte);
                const f16x8 asq = *(const f16x8*)(sSq + byte);
                acc[0] = __builtin_amdgcn_mfma_f32_16x16x32_f16(ah,  bfr[0][kk], acc[0], 0, 0, 0);
                acc[1] = __builtin_amdgcn_mfma_f32_16x16x32_f16(ah,  bfr[1][kk], acc[1], 0, 0, 0);
                accS   = __builtin_amdgcn_mfma_f32_16x16x32_f16(ah,  onesf, accS,  0, 0, 0);
                accS2  = __builtin_amdgcn_mfma_f32_16x16x32_f16(asq, onesf, accS2, 0, 0, 0);
            }
#pragma unroll
            for (int jr = 0; jr < 4; ++jr) {
                const float m_  = accS[jr] * (1.f / C);
                const float var = accS2[jr] * (1.f / C) - m_ * m_;
                const float inv = rsqrtf(var + LNEPS * OSC * OSC);
#pragma unroll
                for (int nt = 0; nt < 2; ++nt)
                    out[((size_t)i * NRES + j0 + mt * 16 + (l >> 4) * 4 + jr) * C +
                        w * 32 + nt * 16 + (l & 15)] =
                        (acc[nt][jr] - m_ * sQ[nt]) * inv + cB[nt];
            }
        }
        __syncthreads();
    }
}

extern "C" void kernel_launch(void* const* d_in, const int* in_sizes, int n_in,
                              void* d_out, int out_size, void* d_ws, size_t ws_size,
                              hipStream_t stream) {
    const float* act_s = (const float*)d_in[0];
    const float* act_r = (const float*)d_in[1];
    const float* mask  = (const float*)d_in[2];
    const float* ln_g  = (const float*)d_in[3];
    const float* ln_b  = (const float*)d_in[4];
    const float* w_lp  = (const float*)d_in[5];
    const float* b_lp  = (const float*)d_in[6];
    const float* w_rp  = (const float*)d_in[7];
    const float* b_rp  = (const float*)d_in[8];
    const float* w_lg  = (const float*)d_in[9];
    const float* b_lg  = (const float*)d_in[10];
    const float* w_rg  = (const float*)d_in[11];
    const float* b_rg  = (const float*)d_in[12];
    const float* ln_cg = (const float*)d_in[13];
    const float* ln_cb = (const float*)d_in[14];
    const float* w_out = (const float*)d_in[15];
    const float* b_out = (const float*)d_in[16];
    float* out = (float*)d_out;

    float* part       = (float*)d_ws;              // [2][ACH][768][128]
    float* left_line  = part + (size_t)2 * ACH * NRES * C;
    float* right_line = left_line + NRES * C;

    line_all<<<2 * LHALF, 256, 0, stream>>>(act_s, act_r, mask, ln_g, ln_b,
                                            w_lp, b_lp, w_rp, b_rp,
                                            w_lg, b_lg, w_rg, b_rg, part);
    reduce2<<<768, 256, 0, stream>>>(part, left_line, right_line);
    out_mfma<<<NRES, 256, 0, stream>>>(left_line, right_line, ln_cg, ln_cb,
                                       w_out, b_out, out);
}

// Round 18
// 326.743 us; speedup vs baseline: 1.5733x; 1.1971x over previous
//
#include <hip/hip_runtime.h>
#include <math.h>

#define NRES 768
#define C    128
#define LNEPS 1e-5f
#define TA   16             // a-values per block (phase A)
#define ACH  48             // a-chunks = 768/TA
#define MI   16             // i-rows per block (phase A)
#define NIT  (NRES / MI)    // 48 i-tiles
#define XBUF (MI * 256)     // bytes per LDS plane (phase A)
#define LHALF (ACH * NIT)   // blocks per half in line_all
#define OSC  0.015625f      // 1/64: out-kernel staging scale (fp16 range guard)

typedef __attribute__((ext_vector_type(8))) short    bf16x8;
typedef __attribute__((ext_vector_type(8))) _Float16 f16x8;
typedef __attribute__((ext_vector_type(4))) float    f32x4;

// ---------------- bf16 path (line_all) ----------------
// pack the top16 of two f32 bit-patterns: lo word <- u0>>16, hi word <- u1 top
__device__ __forceinline__ uint32_t pack_hi(uint32_t u0, uint32_t u1) {
    return (u1 & 0xFFFF0000u) | (u0 >> 16);
}

// truncation-based split: x ~= hi + lo, hi = trunc16(x), lo = trunc16(x - hi).
__device__ __forceinline__ void split2t(float a, float b, uint32_t& hi, uint32_t& lo) {
    const uint32_t ua = __float_as_uint(a), ub = __float_as_uint(b);
    const float ra = a - __uint_as_float(ua & 0xFFFF0000u);
    const float rb = b - __uint_as_float(ub & 0xFFFF0000u);
    hi = pack_hi(ua, ub);
    lo = pack_hi(__float_as_uint(ra), __float_as_uint(rb));
}

// Stage one row-segment (4 cols) as hi/lo/sq bf16 planes, XOR-swizzled
// ((row&15)<<4 key — the proven zero-conflict layout). Pure local VALU.
__device__ __forceinline__ void stage_row3(const float4& x, int row, int t,
                                           char* hiB, char* loB, char* sqB) {
    const int byte = (row * 256 + 8 * (t & 31)) ^ ((row & 15) << 4);
    uint2 uh, ul, uq;
    split2t(x.x, x.y, uh.x, ul.x);
    split2t(x.z, x.w, uh.y, ul.y);
    uq.x = pack_hi(__float_as_uint(x.x * x.x), __float_as_uint(x.y * x.y));
    uq.y = pack_hi(__float_as_uint(x.z * x.z), __float_as_uint(x.w * x.w));
    *(uint2*)(hiB + byte) = uh;
    *(uint2*)(loB + byte) = ul;
    *(uint2*)(sqB + byte) = uq;
}

// round-to-nearest-even f32 -> bf16 bits (weight quantization)
__device__ __forceinline__ uint32_t bf16rn(float f) {
    uint32_t u = __float_as_uint(f);
    return (u + 0x7FFFu + ((u >> 16) & 1u)) >> 16;
}

// ---------------- fp16 path (out_mfma) ----------------
__device__ __forceinline__ uint32_t pk_f16rn(float a, float b) {
    _Float16 ha = (_Float16)a, hb = (_Float16)b;   // RTN converts
    const uint32_t ua = *(const unsigned short*)&ha;
    const uint32_t ub = *(const unsigned short*)&hb;
    return ua | (ub << 16);
}

__device__ __forceinline__ void stage_row2(const float4& x, int row, int t,
                                           char* hiB, char* sqB) {
    const int byte = (row * 256 + 8 * (t & 31)) ^ ((row & 15) << 4);
    uint2 uh, uq;
    uh.x = pk_f16rn(x.x, x.y);
    uh.y = pk_f16rn(x.z, x.w);
    uq.x = pk_f16rn(x.x * x.x, x.y * x.y);
    uq.y = pk_f16rn(x.z * x.z, x.w * x.w);
    *(uint2*)(hiB + byte) = uh;
    *(uint2*)(sqB + byte) = uq;
}

// ---------------------------------------------------------------------------
// Phase A (both halves in ONE launch): partial line sums.   [R11 verbatim —
// best measured line kernel: 268 us, MfmaUtil 25.5 + VALUBusy 56 = 81% busy]
// line[i,c] = sum_a [mask[a,i]] * P(a,i,c) * sigmoid(G(a,i,c))
// [P|G](a,i,:) = LN(act[a,i,:]) @ [wP|wG] + bias
// LN folded: P_n = inv*(x@W'q - m*sumW'q) + (b@W + bias), W'q = bf16(g_k W_kn).
// Row stats BY MFMA: Sx = mfma(x_hi, ones), Sx^2 = mfma(trunc16(x^2), ones).
// P uses hi+lo; G (inside sigmoid) uses hi only.
// Blocks 0..LHALF-1: act_s -> part[0]; LHALF..: act_r (masked) -> part[1].
// ---------------------------------------------------------------------------
__global__ __launch_bounds__(256, 3) void line_all(
    const float* __restrict__ act_s, const float* __restrict__ act_r,
    const float* __restrict__ mask,
    const float* __restrict__ ln_g, const float* __restrict__ ln_b,
    const float* __restrict__ w_lp, const float* __restrict__ b_lp,
    const float* __restrict__ w_rp, const float* __restrict__ b_rp,
    const float* __restrict__ w_lg, const float* __restrict__ b_lg,
    const float* __restrict__ w_rg, const float* __restrict__ b_rg,
    float* __restrict__ part)        // [2][ACH][768][128]
{
    __shared__ char  sHi[XBUF];      // bf16 [16 rows][128 c], XOR-swizzled
    __shared__ char  sLo[XBUF];
    __shared__ char  sSq[XBUF];
    __shared__ float sM[TA * MI];

    const int t = threadIdx.x;
    const int w = t >> 6;            // wave 0..3
    const int l = t & 63;
    const int right = (blockIdx.x >= LHALF);
    const int bid2  = blockIdx.x - right * LHALF;
    const int i0  = (bid2 % NIT) * MI;
    const int ach = bid2 / NIT;
    const int a0  = ach * TA;

    const float* act = right ? act_r : act_s;
    const float* wP  = right ? w_rp : w_lp;
    const float* bP  = right ? b_rp : b_lp;
    const float* wG  = right ? w_rg : w_lg;
    const float* bG  = right ? b_rg : b_lg;

    // --- B-fragments: W'q = bf16(g_k*W[k][n]); per-col constants:
    //     sQ[nt] = sum_k W'q[k][n], cB[nt] = sum_k b_k*W[k][n] + bias_n
    bf16x8 bfr[4][4];                // [nt][kk]; nt 0,1 = P, nt 2,3 = G
    float  sQ[4], cB[4];
#pragma unroll
    for (int nt = 0; nt < 4; ++nt) {
        const float* wsrc = (nt < 2) ? wP : wG;
        const int n = w * 32 + (nt & 1) * 16 + (l & 15);
        float sacc = 0.f, tacc = 0.f;
#pragma unroll
        for (int kk = 0; kk < 4; ++kk) {
            bf16x8 f;
#pragma unroll
            for (int jj = 0; jj < 8; ++jj) {
                const int k = kk * 32 + (l >> 4) * 8 + jj;
                const float wv = wsrc[k * C + n];
                const uint32_t q = bf16rn(ln_g[k] * wv);
                f[jj] = (short)q;
                sacc += __uint_as_float(q << 16);
                tacc += ln_b[k] * wv;
            }
            bfr[nt][kk] = f;
        }
        // complete the k-sum over the 4 lane-groups sharing this n
        sacc += __shfl_xor(sacc, 16); sacc += __shfl_xor(sacc, 32);
        tacc += __shfl_xor(tacc, 16); tacc += __shfl_xor(tacc, 32);
        sQ[nt] = sacc;
        cB[nt] = tacc + ((nt < 2) ? bP[n] : bG[n]);
    }

    bf16x8 onesf;
#pragma unroll
    for (int jj = 0; jj < 8; ++jj) onesf[jj] = (short)0x3F80;  // bf16 1.0

    if (right) {
        // sM[al*16 + r] = mask[a0+al][i0+r]
        sM[t] = mask[(size_t)(a0 + (t >> 4)) * NRES + i0 + (t & 15)];
    }

    float lacc[2][4];
#pragma unroll
    for (int ntp = 0; ntp < 2; ++ntp)
#pragma unroll
        for (int jr = 0; jr < 4; ++jr) lacc[ntp][jr] = 0.f;

    const float* srcbase = act + (size_t)a0 * (NRES * C) + (size_t)i0 * C;

    // prologue: load a=0 (2 float4/thread covers 16 rows x 128 c)
    float4 xv[2], xn[2];
#pragma unroll
    for (int j = 0; j < 2; ++j)
        xv[j] = *(const float4*)(srcbase + 4 * (t + 256 * j));

    for (int al = 0; al < TA; ++al) {
        // issue next step's loads early (hide HBM under stage+MFMA)
        if (al + 1 < TA) {
            const float* srcn = srcbase + (size_t)(al + 1) * (NRES * C);
#pragma unroll
            for (int j = 0; j < 2; ++j)
                xn[j] = *(const float4*)(srcn + 4 * (t + 256 * j));
        }

#pragma unroll
        for (int j = 0; j < 2; ++j)
            stage_row3(xv[j], (t >> 5) + 8 * j, t, sHi, sLo, sSq);
        __syncthreads();

        const f32x4 zero = {0.f, 0.f, 0.f, 0.f};
        f32x4 acc[4], accS = zero, accS2 = zero;
#pragma unroll
        for (int nt = 0; nt < 4; ++nt) acc[nt] = zero;

#pragma unroll
        for (int kk = 0; kk < 4; ++kk) {
            const int row  = l & 15;
            const int byte = (row * 256 + (kk * 32 + (l >> 4) * 8) * 2) ^ ((row & 15) << 4);
            const bf16x8 ah  = *(const bf16x8*)(sHi + byte);
            const bf16x8 alo = *(const bf16x8*)(sLo + byte);
            const bf16x8 asq = *(const bf16x8*)(sSq + byte);
            acc[0] = __builtin_amdgcn_mfma_f32_16x16x32_bf16(ah,  bfr[0][kk], acc[0], 0, 0, 0);
            acc[0] = __builtin_amdgcn_mfma_f32_16x16x32_bf16(alo, bfr[0][kk], acc[0], 0, 0, 0);
            acc[1] = __builtin_amdgcn_mfma_f32_16x16x32_bf16(ah,  bfr[1][kk], acc[1], 0, 0, 0);
            acc[1] = __builtin_amdgcn_mfma_f32_16x16x32_bf16(alo, bfr[1][kk], acc[1], 0, 0, 0);
            acc[2] = __builtin_amdgcn_mfma_f32_16x16x32_bf16(ah,  bfr[2][kk], acc[2], 0, 0, 0);
            acc[3] = __builtin_amdgcn_mfma_f32_16x16x32_bf16(ah,  bfr[3][kk], acc[3], 0, 0, 0);
            accS   = __builtin_amdgcn_mfma_f32_16x16x32_bf16(ah,  onesf, accS,  0, 0, 0);
            accS2  = __builtin_amdgcn_mfma_f32_16x16x32_bf16(asq, onesf, accS2, 0, 0, 0);
        }

        float mk[4] = {1.f, 1.f, 1.f, 1.f};
        if (right) {
            const float4 m4 = *(const float4*)&sM[al * MI + (l >> 4) * 4];
            mk[0] = m4.x; mk[1] = m4.y; mk[2] = m4.z; mk[3] = m4.w;
        }
#pragma unroll
        for (int jr = 0; jr < 4; ++jr) {
            const float m_  = accS[jr] * (1.f / C);
            const float var = accS2[jr] * (1.f / C) - m_ * m_;
            const float inv = rsqrtf(var + LNEPS);
#pragma unroll
            for (int ntp = 0; ntp < 2; ++ntp) {
                const float P = (acc[ntp][jr]     - m_ * sQ[ntp])     * inv + cB[ntp];
                const float G = (acc[ntp + 2][jr] - m_ * sQ[ntp + 2]) * inv + cB[ntp + 2];
                const float sg = __builtin_amdgcn_rcpf(1.f + __expf(-G));
                lacc[ntp][jr] += P * sg * mk[jr];
            }
        }
        __syncthreads();   // all waves done reading planes before next stage

        xv[0] = xn[0]; xv[1] = xn[1];
    }

    float* dst = part + ((size_t)right * ACH + ach) * (NRES * C);
#pragma unroll
    for (int ntp = 0; ntp < 2; ++ntp)
#pragma unroll
        for (int jr = 0; jr < 4; ++jr)
            dst[(size_t)(i0 + (l >> 4) * 4 + jr) * C +
                w * 32 + ntp * 16 + (l & 15)] = lacc[ntp][jr];
}

// both halves reduced in one launch: blocks 0..383 -> left, 384..767 -> right
__global__ __launch_bounds__(256) void reduce2(const float* __restrict__ part,
                                               float* __restrict__ left_line,
                                               float* __restrict__ right_line) {
    const int half = (blockIdx.x >= 384);
    const int idx  = (blockIdx.x - half * 384) * 256 + threadIdx.x;  // < 98304
    const float* p = part + (size_t)half * ACH * NRES * C;
    float s = 0.f;
#pragma unroll 8
    for (int q = 0; q < ACH; ++q) s += p[(size_t)q * (NRES * C) + idx];
    (half ? right_line : left_line)[idx] = s;
}

// ---------------------------------------------------------------------------
// Phase B: out[i,j,:] = LN(l[i,:]*r[j,:]) @ w_out + b_out   [R13 verbatim —
// fp16 operands, 4 MFMA/mt vs bf16's 6, 2 LDS planes vs 3; ~34 us]
// RANGE GUARD: stage p' = p/64 (LN scale-invariant with eps' = eps/64^2) —
// unscaled p*p overflowed fp16. One block per i, looping 12 j-tiles.
// ---------------------------------------------------------------------------
__global__ __launch_bounds__(256, 3) void out_mfma(
    const float* __restrict__ lline,   // [768,128]
    const float* __restrict__ rline,   // [768,128]
    const float* __restrict__ cg, const float* __restrict__ cb,
    const float* __restrict__ wO, const float* __restrict__ bO,
    float* __restrict__ out)           // [768,768,128]
{
    __shared__ char sHi[64 * 256];
    __shared__ char sSq[64 * 256];

    const int t = threadIdx.x;
    const int w = t >> 6;
    const int l = t & 63;
    const int i = blockIdx.x;

    f16x8 bfr[2][4];
    float sQ[2], cB[2];
#pragma unroll
    for (int nt = 0; nt < 2; ++nt) {
        const int n = w * 32 + nt * 16 + (l & 15);
        float sacc = 0.f, tacc = 0.f;
#pragma unroll
        for (int kk = 0; kk < 4; ++kk) {
            f16x8 f;
#pragma unroll
            for (int jj = 0; jj < 8; ++jj) {
                const int k = kk * 32 + (l >> 4) * 8 + jj;
                const float wv = wO[k * C + n];
                const _Float16 q = (_Float16)(cg[k] * wv);   // RTN
                f[jj] = q;
                sacc += (float)q;
                tacc += cb[k] * wv;
            }
            bfr[nt][kk] = f;
        }
        sacc += __shfl_xor(sacc, 16); sacc += __shfl_xor(sacc, 32);
        tacc += __shfl_xor(tacc, 16); tacc += __shfl_xor(tacc, 32);
        sQ[nt] = sacc;
        cB[nt] = tacc + bO[n];
    }

    f16x8 onesf;
#pragma unroll
    for (int jj = 0; jj < 8; ++jj) onesf[jj] = (_Float16)1.0f;

    const int c4 = 4 * (t & 31);
    // fold the 1/64 staging scale into the left-line preload
    float4 l4 = *(const float4*)(lline + (size_t)i * C + c4);
    l4.x *= OSC; l4.y *= OSC; l4.z *= OSC; l4.w *= OSC;

    for (int jt = 0; jt < 12; ++jt) {
        const int j0 = jt * 64;
        const float* rsrc = rline + (size_t)j0 * C;

        // hoist the 8 tile loads, then convert+stage
        float4 rv[8];
#pragma unroll
        for (int j = 0; j < 8; ++j)
            rv[j] = *(const float4*)(rsrc + 4 * (t + 256 * j));
#pragma unroll
        for (int j = 0; j < 8; ++j) {
            float4 p;
            p.x = l4.x * rv[j].x; p.y = l4.y * rv[j].y;
            p.z = l4.z * rv[j].z; p.w = l4.w * rv[j].w;
            stage_row2(p, (t >> 5) + 8 * j, t, sHi, sSq);
        }
        __syncthreads();

        const f32x4 zero = {0.f, 0.f, 0.f, 0.f};
#pragma unroll
        for (int mt = 0; mt < 4; ++mt) {
            f32x4 acc[2], accS = zero, accS2 = zero;
#pragma unroll
            for (int nt = 0; nt < 2; ++nt) acc[nt] = zero;
#pragma unroll
            for (int kk = 0; kk < 4; ++kk) {
                const int row  = mt * 16 + (l & 15);
                const int byte = (row * 256 + (kk * 32 + (l >> 4) * 8) * 2) ^ ((row & 15) << 4);
                const f16x8 ah  = *(const f16x8*)(sHi + byte);
                const f16x8 asq = *(const f16x8*)(sSq + byte);
                acc[0] = __builtin_amdgcn_mfma_f32_16x16x32_f16(ah,  bfr[0][kk], acc[0], 0, 0, 0);
                acc[1] = __builtin_amdgcn_mfma_f32_16x16x32_f16(ah,  bfr[1][kk], acc[1], 0, 0, 0);
                accS   = __builtin_amdgcn_mfma_f32_16x16x32_f16(ah,  onesf, accS,  0, 0, 0);
                accS2  = __builtin_amdgcn_mfma_f32_16x16x32_f16(asq, onesf, accS2, 0, 0, 0);
            }
#pragma unroll
            for (int jr = 0; jr < 4; ++jr) {
                const float m_  = accS[jr] * (1.f / C);
                const float var = accS2[jr] * (1.f / C) - m_ * m_;
                const float inv = rsqrtf(var + LNEPS * OSC * OSC);  // eps' = eps/64^2
#pragma unroll
                for (int nt = 0; nt < 2; ++nt)
                    out[((size_t)i * NRES + j0 + mt * 16 + (l >> 4) * 4 + jr) * C +
                        w * 32 + nt * 16 + (l & 15)] =
                        (acc[nt][jr] - m_ * sQ[nt]) * inv + cB[nt];
            }
        }
        __syncthreads();   // protect planes before next tile's stage
    }
}

extern "C" void kernel_launch(void* const* d_in, const int* in_sizes, int n_in,
                              void* d_out, int out_size, void* d_ws, size_t ws_size,
                              hipStream_t stream) {
    const float* act_s = (const float*)d_in[0];
    const float* act_r = (const float*)d_in[1];
    const float* mask  = (const float*)d_in[2];
    const float* ln_g  = (const float*)d_in[3];
    const float* ln_b  = (const float*)d_in[4];
    const float* w_lp  = (const float*)d_in[5];
    const float* b_lp  = (const float*)d_in[6];
    const float* w_rp  = (const float*)d_in[7];
    const float* b_rp  = (const float*)d_in[8];
    const float* w_lg  = (const float*)d_in[9];
    const float* b_lg  = (const float*)d_in[10];
    const float* w_rg  = (const float*)d_in[11];
    const float* b_rg  = (const float*)d_in[12];
    const float* ln_cg = (const float*)d_in[13];
    const float* ln_cb = (const float*)d_in[14];
    const float* w_out = (const float*)d_in[15];
    const float* b_out = (const float*)d_in[16];
    float* out = (float*)d_out;

    float* part       = (float*)d_ws;              // [2][ACH][768][128]
    float* left_line  = part + (size_t)2 * ACH * NRES * C;
    float* right_line = left_line + NRES * C;

    line_all<<<2 * LHALF, 256, 0, stream>>>(act_s, act_r, mask, ln_g, ln_b,
                                            w_lp, b_lp, w_rp, b_rp,
                                            w_lg, b_lg, w_rg, b_rg, part);
    reduce2<<<768, 256, 0, stream>>>(part, left_line, right_line);
    out_mfma<<<NRES, 256, 0, stream>>>(left_line, right_line, ln_cg, ln_cb,
                                       w_out, b_out, out);
}